// Round 1
// baseline (718.191 us; speedup 1.0000x reference)
//
#include <hip/hip_runtime.h>
#include <hip/hip_bf16.h>

#define NN 100000
#define NE 1600000
#define D 128

// ---------------- CSR build ----------------
__global__ void k_count(const int* __restrict__ dst, int* __restrict__ deg) {
  int e = blockIdx.x * blockDim.x + threadIdx.x;
  if (e < NE) atomicAdd(&deg[dst[e]], 1);
}

__global__ void k_scan1(const int* __restrict__ deg, int* __restrict__ incl,
                        int* __restrict__ bsum) {
  __shared__ int s[256];
  int t = threadIdx.x;
  int i = blockIdx.x * 256 + t;
  int v = (i < NN) ? deg[i] : 0;
  s[t] = v; __syncthreads();
  for (int off = 1; off < 256; off <<= 1) {
    int u = (t >= off) ? s[t - off] : 0;
    __syncthreads();
    s[t] += u; __syncthreads();
  }
  if (i < NN) incl[i] = s[t];
  if (t == 255) bsum[blockIdx.x] = s[255];
}

__global__ void k_scan2(int* __restrict__ bsum, int nb) {
  __shared__ int s[512];
  int t = threadIdx.x;
  int v = (t < nb) ? bsum[t] : 0;
  s[t] = v; __syncthreads();
  for (int off = 1; off < 512; off <<= 1) {
    int u = (t >= off) ? s[t - off] : 0;
    __syncthreads();
    s[t] += u; __syncthreads();
  }
  if (t < nb) bsum[t] = s[t] - v;  // exclusive block offsets
}

__global__ void k_scan3(const int* __restrict__ incl, const int* __restrict__ deg,
                        const int* __restrict__ bsum, int* __restrict__ rowstart) {
  int i = blockIdx.x * 256 + threadIdx.x;
  if (i < NN) {
    int ex = incl[i] - deg[i] + bsum[blockIdx.x];
    rowstart[i] = ex;
    if (i == NN - 1) rowstart[NN] = ex + deg[i];
  }
}

__global__ void k_fill(const int* __restrict__ src, const int* __restrict__ dst,
                       const int* __restrict__ rowstart, int* __restrict__ cursor,
                       int* __restrict__ col) {
  int e = blockIdx.x * blockDim.x + threadIdx.x;
  if (e < NE) {
    int d = dst[e];
    int p = atomicAdd(&cursor[d], 1);
    col[rowstart[d] + p] = src[e];
  }
}

// ---------------- mean aggregation: one wave per node ----------------
__global__ __launch_bounds__(256) void k_aggregate(const float* __restrict__ feat,
    const int* __restrict__ rowstart, const int* __restrict__ col,
    float* __restrict__ out) {
  int wid = threadIdx.x >> 6;
  int lane = threadIdx.x & 63;
  int node = blockIdx.x * 4 + wid;
  if (node >= NN) return;
  int b = rowstart[node], e = rowstart[node + 1];
  float ax = 0.f, ay = 0.f;
  for (int j = b; j < e; ++j) {
    int s = col[j];
    const float2 v = *reinterpret_cast<const float2*>(&feat[(size_t)s * D + lane * 2]);
    ax += v.x; ay += v.y;
  }
  float inv = (e > b) ? 1.f / (float)(e - b) : 0.f;
  float2 o; o.x = ax * inv; o.y = ay * inv;
  *reinterpret_cast<float2*>(&out[(size_t)node * D + lane * 2]) = o;
}

// ---------------- fused dual GEMM: C = act(A@W1 + B@W2 + bias) ----------------
// 64 rows/block, 256 threads; thread: 4 rows (g*4..) x 8 cols (cg*4..+3, 64+cg*4..+3)
__global__ __launch_bounds__(256) void k_gemm_dual(
    const float* __restrict__ A, const float* __restrict__ B,
    const float* __restrict__ W1, const float* __restrict__ W2,
    const float* __restrict__ bias, float* __restrict__ C, int relu)
{
  __shared__ float At[32][65];   // k-major, +1 pad (writes conflict-free)
  __shared__ float Wc[32 * 128];
  const int t = threadIdx.x;
  const int rowbase = blockIdx.x * 64;
  const int g = t >> 4;    // 0..15 -> rows g*4..g*4+3
  const int cg = t & 15;   // cols cg*4..+3 and 64+cg*4..+3
  float acc[4][8] = {};

  for (int phase = 0; phase < 2; ++phase) {
    const float* M = phase ? B : A;
    const float* W = phase ? W2 : W1;
    for (int kb = 0; kb < D; kb += 32) {
      __syncthreads();
      { // stage A-tile transposed: rows rowbase..+63, k kb..kb+31
        int row = t >> 2;
        int kl = (t & 3) * 8;
        int gr = rowbase + row;
        float4 v0 = {0, 0, 0, 0}, v1 = {0, 0, 0, 0};
        if (gr < NN) {
          v0 = *reinterpret_cast<const float4*>(&M[(size_t)gr * D + kb + kl]);
          v1 = *reinterpret_cast<const float4*>(&M[(size_t)gr * D + kb + kl + 4]);
        }
        At[kl + 0][row] = v0.x; At[kl + 1][row] = v0.y;
        At[kl + 2][row] = v0.z; At[kl + 3][row] = v0.w;
        At[kl + 4][row] = v1.x; At[kl + 5][row] = v1.y;
        At[kl + 6][row] = v1.z; At[kl + 7][row] = v1.w;
      }
      { // stage W chunk [32][128] flat
        #pragma unroll
        for (int q = 0; q < 4; ++q) {
          int fi = t + 256 * q;        // float4 index
          int k = fi >> 5;
          int c = (fi & 31) * 4;
          *reinterpret_cast<float4*>(&Wc[fi * 4]) =
              *reinterpret_cast<const float4*>(&W[(size_t)(kb + k) * D + c]);
        }
      }
      __syncthreads();
      #pragma unroll
      for (int k = 0; k < 32; ++k) {
        float4 w0 = *reinterpret_cast<float4*>(&Wc[k * 128 + cg * 4]);
        float4 w1 = *reinterpret_cast<float4*>(&Wc[k * 128 + 64 + cg * 4]);
        #pragma unroll
        for (int r = 0; r < 4; ++r) {
          float a = At[k][g * 4 + r];
          acc[r][0] += a * w0.x; acc[r][1] += a * w0.y;
          acc[r][2] += a * w0.z; acc[r][3] += a * w0.w;
          acc[r][4] += a * w1.x; acc[r][5] += a * w1.y;
          acc[r][6] += a * w1.z; acc[r][7] += a * w1.w;
        }
      }
    }
  }
  // epilogue
  #pragma unroll
  for (int r = 0; r < 4; ++r) {
    int gr = rowbase + g * 4 + r;
    if (gr < NN) {
      float4 o0, o1;
      o0.x = acc[r][0] + bias[cg * 4 + 0];
      o0.y = acc[r][1] + bias[cg * 4 + 1];
      o0.z = acc[r][2] + bias[cg * 4 + 2];
      o0.w = acc[r][3] + bias[cg * 4 + 3];
      o1.x = acc[r][4] + bias[64 + cg * 4 + 0];
      o1.y = acc[r][5] + bias[64 + cg * 4 + 1];
      o1.z = acc[r][6] + bias[64 + cg * 4 + 2];
      o1.w = acc[r][7] + bias[64 + cg * 4 + 3];
      if (relu) {
        o0.x = fmaxf(o0.x, 0.f); o0.y = fmaxf(o0.y, 0.f);
        o0.z = fmaxf(o0.z, 0.f); o0.w = fmaxf(o0.w, 0.f);
        o1.x = fmaxf(o1.x, 0.f); o1.y = fmaxf(o1.y, 0.f);
        o1.z = fmaxf(o1.z, 0.f); o1.w = fmaxf(o1.w, 0.f);
      }
      *reinterpret_cast<float4*>(&C[(size_t)gr * D + cg * 4]) = o0;
      *reinterpret_cast<float4*>(&C[(size_t)gr * D + 64 + cg * 4]) = o1;
    }
  }
}

// ---------------- layer 3: per-node scalars z = h.Wl3, r = h.Wr3 + b3 ----------------
__global__ __launch_bounds__(256) void k_zr(const float* __restrict__ H,
    const float* __restrict__ Wl, const float* __restrict__ Wr,
    const float* __restrict__ b3, float* __restrict__ z, float* __restrict__ r) {
  int wid = threadIdx.x >> 6, lane = threadIdx.x & 63;
  int node = blockIdx.x * 4 + wid;
  if (node >= NN) return;
  float2 h = *reinterpret_cast<const float2*>(&H[(size_t)node * D + lane * 2]);
  float sl = h.x * Wl[lane * 2] + h.y * Wl[lane * 2 + 1];
  float sr = h.x * Wr[lane * 2] + h.y * Wr[lane * 2 + 1];
  for (int m = 32; m >= 1; m >>= 1) {
    sl += __shfl_xor(sl, m, 64);
    sr += __shfl_xor(sr, m, 64);
  }
  if (lane == 0) { z[node] = sl; r[node] = sr + b3[0]; }
}

__global__ void k_out(const float* __restrict__ z, const float* __restrict__ r,
    const int* __restrict__ rowstart, const int* __restrict__ col,
    float* __restrict__ out) {
  int n = blockIdx.x * 256 + threadIdx.x;
  if (n >= NN) return;
  int b = rowstart[n], e = rowstart[n + 1];
  float s = 0.f;
  for (int j = b; j < e; ++j) s += z[col[j]];
  float inv = (e > b) ? 1.f / (float)(e - b) : 0.f;
  out[n] = r[n] + s * inv;
}

extern "C" void kernel_launch(void* const* d_in, const int* in_sizes, int n_in,
                              void* d_out, int out_size, void* d_ws, size_t ws_size,
                              hipStream_t stream) {
  const float* x   = (const float*)d_in[0];
  const int*   ei  = (const int*)d_in[1];
  const float* Wl1 = (const float*)d_in[2];
  const float* Wr1 = (const float*)d_in[3];
  const float* b1  = (const float*)d_in[4];
  const float* Wl2 = (const float*)d_in[5];
  const float* Wr2 = (const float*)d_in[6];
  const float* b2  = (const float*)d_in[7];
  const float* Wl3 = (const float*)d_in[8];
  const float* Wr3 = (const float*)d_in[9];
  const float* b3  = (const float*)d_in[10];
  const int* srcv = ei;
  const int* dstv = ei + NE;
  float* out = (float*)d_out;

  char* ws = (char*)d_ws;
  size_t off = 0;
  auto alloc = [&](size_t bytes) {
    size_t o = off;
    off += (bytes + 255) & ~(size_t)255;
    return o;
  };
  int* deg      = (int*)(ws + alloc((size_t)NN * 4));
  int* incl     = (int*)(ws + alloc((size_t)NN * 4));
  int* rowstart = (int*)(ws + alloc((size_t)(NN + 1) * 4));
  int* cursor   = (int*)(ws + alloc((size_t)NN * 4));
  int* col      = (int*)(ws + alloc((size_t)NE * 4));
  int* bsum     = (int*)(ws + alloc(512 * 4));
  float* A  = (float*)(ws + alloc((size_t)NN * D * 4));
  float* H1 = (float*)(ws + alloc((size_t)NN * D * 4));
  float* H2 = (float*)(ws + alloc((size_t)NN * D * 4));
  float* z  = (float*)(ws + alloc((size_t)NN * 4));
  float* r  = (float*)(ws + alloc((size_t)NN * 4));

  const int nb_nodes = (NN + 255) / 256;     // 391
  const int nb_edges = (NE + 255) / 256;     // 6250
  const int nb_gemm  = (NN + 63) / 64;       // 1563
  const int nb_wave4 = (NN + 3) / 4;         // 25000

  hipMemsetAsync(deg, 0, (size_t)NN * 4, stream);
  hipMemsetAsync(cursor, 0, (size_t)NN * 4, stream);

  k_count<<<nb_edges, 256, 0, stream>>>(dstv, deg);
  k_scan1<<<nb_nodes, 256, 0, stream>>>(deg, incl, bsum);
  k_scan2<<<1, 512, 0, stream>>>(bsum, nb_nodes);
  k_scan3<<<nb_nodes, 256, 0, stream>>>(incl, deg, bsum, rowstart);
  k_fill<<<nb_edges, 256, 0, stream>>>(srcv, dstv, rowstart, cursor, col);

  // layer 1
  k_aggregate<<<nb_wave4, 256, 0, stream>>>(x, rowstart, col, A);
  k_gemm_dual<<<nb_gemm, 256, 0, stream>>>(A, x, Wl1, Wr1, b1, H1, 1);
  // layer 2
  k_aggregate<<<nb_wave4, 256, 0, stream>>>(H1, rowstart, col, A);
  k_gemm_dual<<<nb_gemm, 256, 0, stream>>>(A, H1, Wl2, Wr2, b2, H2, 1);
  // layer 3 (D_OUT = 1): aggregate scalars
  k_zr<<<nb_wave4, 256, 0, stream>>>(H2, Wl3, Wr3, b3, z, r);
  k_out<<<nb_nodes, 256, 0, stream>>>(z, r, rowstart, col, out);
}

// Round 2
// 688.617 us; speedup vs baseline: 1.0429x; 1.0429x over previous
//
#include <hip/hip_runtime.h>
#include <hip/hip_bf16.h>

#define NN 100000
#define NE 1600000
#define D 128

typedef unsigned short u16;
typedef unsigned int u32;
typedef __attribute__((ext_vector_type(8))) short bf16x8;
typedef __attribute__((ext_vector_type(4))) float f32x4;
typedef __attribute__((ext_vector_type(8))) u16 u16x8;

__device__ inline u16 f2b(float f) {
  union { float f; u32 u; } v; v.f = f;
  u32 u = v.u;
  return (u16)((u + 0x7fffu + ((u >> 16) & 1u)) >> 16);
}

// ---------------- CSR build ----------------
__global__ void k_count(const int* __restrict__ dst, int* __restrict__ deg) {
  int e = blockIdx.x * blockDim.x + threadIdx.x;
  if (e < NE) atomicAdd(&deg[dst[e]], 1);
}

__global__ void k_scan1(const int* __restrict__ deg, int* __restrict__ incl,
                        int* __restrict__ bsum) {
  __shared__ int s[256];
  int t = threadIdx.x;
  int i = blockIdx.x * 256 + t;
  int v = (i < NN) ? deg[i] : 0;
  s[t] = v; __syncthreads();
  for (int off = 1; off < 256; off <<= 1) {
    int u = (t >= off) ? s[t - off] : 0;
    __syncthreads();
    s[t] += u; __syncthreads();
  }
  if (i < NN) incl[i] = s[t];
  if (t == 255) bsum[blockIdx.x] = s[255];
}

__global__ void k_scan2(int* __restrict__ bsum, int nb) {
  __shared__ int s[512];
  int t = threadIdx.x;
  int v = (t < nb) ? bsum[t] : 0;
  s[t] = v; __syncthreads();
  for (int off = 1; off < 512; off <<= 1) {
    int u = (t >= off) ? s[t - off] : 0;
    __syncthreads();
    s[t] += u; __syncthreads();
  }
  if (t < nb) bsum[t] = s[t] - v;  // exclusive block offsets
}

__global__ void k_scan3(const int* __restrict__ incl, const int* __restrict__ deg,
                        const int* __restrict__ bsum, int* __restrict__ rowstart) {
  int i = blockIdx.x * 256 + threadIdx.x;
  if (i < NN) {
    int ex = incl[i] - deg[i] + bsum[blockIdx.x];
    rowstart[i] = ex;
    if (i == NN - 1) rowstart[NN] = ex + deg[i];
  }
}

__global__ void k_fill(const int* __restrict__ src, const int* __restrict__ dst,
                       const int* __restrict__ rowstart, int* __restrict__ cursor,
                       int* __restrict__ col) {
  int e = blockIdx.x * blockDim.x + threadIdx.x;
  if (e < NE) {
    int d = dst[e];
    int p = atomicAdd(&cursor[d], 1);
    col[rowstart[d] + p] = src[e];
  }
}

// ---------------- fp32 -> bf16 bulk convert (8 elems/thread) ----------------
__global__ __launch_bounds__(256) void k_cvt8(const float* __restrict__ in,
                                              u16* __restrict__ out, int n8) {
  int i = blockIdx.x * 256 + threadIdx.x;
  if (i >= n8) return;
  const float4* p = reinterpret_cast<const float4*>(in) + (size_t)i * 2;
  float4 a = p[0], b = p[1];
  u16x8 o;
  o[0] = f2b(a.x); o[1] = f2b(a.y); o[2] = f2b(a.z); o[3] = f2b(a.w);
  o[4] = f2b(b.x); o[5] = f2b(b.y); o[6] = f2b(b.z); o[7] = f2b(b.w);
  *reinterpret_cast<u16x8*>(out + (size_t)i * 8) = o;
}

// ---------------- W (k-major [k][n]) -> Wt (n-major [n][k]) bf16 ----------------
__global__ void k_cvt_wt(const float* __restrict__ W, u16* __restrict__ Wt) {
  int n = blockIdx.x, k = threadIdx.x;
  Wt[n * D + k] = f2b(W[k * D + n]);
}

// ---------------- mean aggregation (bf16 rows): one wave per node ----------------
__global__ __launch_bounds__(256) void k_agg_b(const u16* __restrict__ feat,
    const int* __restrict__ rowstart, const int* __restrict__ col,
    u16* __restrict__ out) {
  int wid = threadIdx.x >> 6;
  int lane = threadIdx.x & 63;
  int node = blockIdx.x * 4 + wid;
  if (node >= NN) return;
  int b = rowstart[node], e = rowstart[node + 1];
  float ax = 0.f, ay = 0.f;
  for (int j = b; j < e; ++j) {
    int s = col[j];
    u32 u = *reinterpret_cast<const u32*>(&feat[(size_t)s * D + lane * 2]);
    union { u32 u; float f; } lo, hi;
    lo.u = u << 16; hi.u = u & 0xffff0000u;
    ax += lo.f; ay += hi.f;
  }
  float inv = (e > b) ? 1.f / (float)(e - b) : 0.f;
  u32 o = (u32)f2b(ax * inv) | ((u32)f2b(ay * inv) << 16);
  *reinterpret_cast<u32*>(&out[(size_t)node * D + lane * 2]) = o;
}

// ---------------- fused dual GEMM via MFMA: C = act(A@Wt1^T + B@Wt2^T + bias) ----
// 256 thr = 4 waves; wave: 16 rows x 128 cols, K=256 (two K=128 GEMMs).
// A/B fragments share slot->k mapping k=(lane>>4)*8+j (HW-mapping invariant).
// C/D layout (verified): col = lane&15, row = (lane>>4)*4 + reg.
__global__ __launch_bounds__(256) void k_gemm_mfma(
    const u16* __restrict__ A, const u16* __restrict__ B,
    const u16* __restrict__ Wt1, const u16* __restrict__ Wt2,
    const float* __restrict__ bias, void* __restrict__ Cout,
    int relu, int out_f32)
{
  int wid = threadIdx.x >> 6, lane = threadIdx.x & 63;
  int rbase = blockIdx.x * 64 + wid * 16;
  if (rbase >= NN) return;
  int l15 = lane & 15, g = lane >> 4;

  int frow = rbase + l15;
  if (frow >= NN) frow = NN - 1;            // safe clamp; OOB rows never stored
  size_t aoff = (size_t)frow * D + g * 8;

  f32x4 acc[8] = {};

  #pragma unroll
  for (int phase = 0; phase < 2; ++phase) {
    const u16* Act = phase ? B : A;
    const u16* Wt  = phase ? Wt2 : Wt1;
    #pragma unroll
    for (int kb = 0; kb < D; kb += 32) {
      bf16x8 af = *reinterpret_cast<const bf16x8*>(&Act[aoff + kb]);
      #pragma unroll
      for (int c = 0; c < 8; ++c) {
        bf16x8 wf = *reinterpret_cast<const bf16x8*>(&Wt[(size_t)(c * 16 + l15) * D + kb + g * 8]);
        acc[c] = __builtin_amdgcn_mfma_f32_16x16x32_bf16(af, wf, acc[c], 0, 0, 0);
      }
    }
  }

  #pragma unroll
  for (int c = 0; c < 8; ++c) {
    float bv = bias[c * 16 + l15];
    #pragma unroll
    for (int r = 0; r < 4; ++r) {
      int row = rbase + g * 4 + r;
      if (row < NN) {
        float v = acc[c][r] + bv;
        if (relu) v = fmaxf(v, 0.f);
        if (out_f32) ((float*)Cout)[(size_t)row * D + c * 16 + l15] = v;
        else         ((u16*)Cout)[(size_t)row * D + c * 16 + l15] = f2b(v);
      }
    }
  }
}

// ---------------- layer 3: per-node scalars z = h.Wl3, r = h.Wr3 + b3 (fp32) ----
__global__ __launch_bounds__(256) void k_zr(const float* __restrict__ H,
    const float* __restrict__ Wl, const float* __restrict__ Wr,
    const float* __restrict__ b3, float* __restrict__ z, float* __restrict__ r) {
  int wid = threadIdx.x >> 6, lane = threadIdx.x & 63;
  int node = blockIdx.x * 4 + wid;
  if (node >= NN) return;
  float2 h = *reinterpret_cast<const float2*>(&H[(size_t)node * D + lane * 2]);
  float sl = h.x * Wl[lane * 2] + h.y * Wl[lane * 2 + 1];
  float sr = h.x * Wr[lane * 2] + h.y * Wr[lane * 2 + 1];
  for (int m = 32; m >= 1; m >>= 1) {
    sl += __shfl_xor(sl, m, 64);
    sr += __shfl_xor(sr, m, 64);
  }
  if (lane == 0) { z[node] = sl; r[node] = sr + b3[0]; }
}

__global__ void k_out(const float* __restrict__ z, const float* __restrict__ r,
    const int* __restrict__ rowstart, const int* __restrict__ col,
    float* __restrict__ out) {
  int n = blockIdx.x * 256 + threadIdx.x;
  if (n >= NN) return;
  int b = rowstart[n], e = rowstart[n + 1];
  float s = 0.f;
  for (int j = b; j < e; ++j) s += z[col[j]];
  float inv = (e > b) ? 1.f / (float)(e - b) : 0.f;
  out[n] = r[n] + s * inv;
}

extern "C" void kernel_launch(void* const* d_in, const int* in_sizes, int n_in,
                              void* d_out, int out_size, void* d_ws, size_t ws_size,
                              hipStream_t stream) {
  const float* x   = (const float*)d_in[0];
  const int*   ei  = (const int*)d_in[1];
  const float* Wl1 = (const float*)d_in[2];
  const float* Wr1 = (const float*)d_in[3];
  const float* b1  = (const float*)d_in[4];
  const float* Wl2 = (const float*)d_in[5];
  const float* Wr2 = (const float*)d_in[6];
  const float* b2  = (const float*)d_in[7];
  const float* Wl3 = (const float*)d_in[8];
  const float* Wr3 = (const float*)d_in[9];
  const float* b3  = (const float*)d_in[10];
  const int* srcv = ei;
  const int* dstv = ei + NE;
  float* out = (float*)d_out;

  char* ws = (char*)d_ws;
  size_t off = 0;
  auto alloc = [&](size_t bytes) {
    size_t o = off;
    off += (bytes + 255) & ~(size_t)255;
    return o;
  };
  int* deg      = (int*)(ws + alloc((size_t)NN * 4));
  int* incl     = (int*)(ws + alloc((size_t)NN * 4));
  int* rowstart = (int*)(ws + alloc((size_t)(NN + 1) * 4));
  int* cursor   = (int*)(ws + alloc((size_t)NN * 4));
  int* col      = (int*)(ws + alloc((size_t)NE * 4));
  int* bsum     = (int*)(ws + alloc(512 * 4));
  u16* xb   = (u16*)(ws + alloc((size_t)NN * D * 2));
  u16* Ab   = (u16*)(ws + alloc((size_t)NN * D * 2));
  u16* H1b  = (u16*)(ws + alloc((size_t)NN * D * 2));
  float* H2 = (float*)(ws + alloc((size_t)NN * D * 4));
  u16* Wt1l = (u16*)(ws + alloc((size_t)D * D * 2));
  u16* Wt1r = (u16*)(ws + alloc((size_t)D * D * 2));
  u16* Wt2l = (u16*)(ws + alloc((size_t)D * D * 2));
  u16* Wt2r = (u16*)(ws + alloc((size_t)D * D * 2));
  float* z  = (float*)(ws + alloc((size_t)NN * 4));
  float* r  = (float*)(ws + alloc((size_t)NN * 4));

  const int nb_nodes = (NN + 255) / 256;     // 391
  const int nb_edges = (NE + 255) / 256;     // 6250
  const int nb_gemm  = (NN + 63) / 64;       // 1563
  const int nb_wave4 = (NN + 3) / 4;         // 25000
  const int nb_cvt   = (NN * D / 8 + 255) / 256;

  hipMemsetAsync(deg, 0, (size_t)NN * 4, stream);
  hipMemsetAsync(cursor, 0, (size_t)NN * 4, stream);

  // CSR
  k_count<<<nb_edges, 256, 0, stream>>>(dstv, deg);
  k_scan1<<<nb_nodes, 256, 0, stream>>>(deg, incl, bsum);
  k_scan2<<<1, 512, 0, stream>>>(bsum, nb_nodes);
  k_scan3<<<nb_nodes, 256, 0, stream>>>(incl, deg, bsum, rowstart);
  k_fill<<<nb_edges, 256, 0, stream>>>(srcv, dstv, rowstart, cursor, col);

  // dtype prep
  k_cvt8<<<nb_cvt, 256, 0, stream>>>(x, xb, NN * D / 8);
  k_cvt_wt<<<D, D, 0, stream>>>(Wl1, Wt1l);
  k_cvt_wt<<<D, D, 0, stream>>>(Wr1, Wt1r);
  k_cvt_wt<<<D, D, 0, stream>>>(Wl2, Wt2l);
  k_cvt_wt<<<D, D, 0, stream>>>(Wr2, Wt2r);

  // layer 1: H1 = relu(agg(x)@Wl1 + x@Wr1 + b1)   (bf16 out)
  k_agg_b<<<nb_wave4, 256, 0, stream>>>(xb, rowstart, col, Ab);
  k_gemm_mfma<<<nb_gemm, 256, 0, stream>>>(Ab, xb, Wt1l, Wt1r, b1, H1b, 1, 0);
  // layer 2: H2 = relu(agg(H1)@Wl2 + H1@Wr2 + b2) (fp32 out for final-layer accuracy)
  k_agg_b<<<nb_wave4, 256, 0, stream>>>(H1b, rowstart, col, Ab);
  k_gemm_mfma<<<nb_gemm, 256, 0, stream>>>(Ab, H1b, Wt2l, Wt2r, b2, H2, 1, 1);
  // layer 3 (D_OUT = 1): aggregate scalar z
  k_zr<<<nb_wave4, 256, 0, stream>>>(H2, Wl3, Wr3, b3, z, r);
  k_out<<<nb_nodes, 256, 0, stream>>>(z, r, rowstart, col, out);
}

// Round 3
// 448.937 us; speedup vs baseline: 1.5998x; 1.5339x over previous
//
#include <hip/hip_runtime.h>
#include <hip/hip_bf16.h>

#define NN 100000
#define NE 1600000
#define D 128

typedef unsigned short u16;
typedef unsigned int u32;
typedef __attribute__((ext_vector_type(8))) short bf16x8;
typedef __attribute__((ext_vector_type(4))) float f32x4;
typedef __attribute__((ext_vector_type(8))) u16 u16x8;

__device__ inline u16 f2b(float f) {
  union { float f; u32 u; } v; v.f = f;
  u32 u = v.u;
  return (u16)((u + 0x7fffu + ((u >> 16) & 1u)) >> 16);
}
__device__ inline float b2f(u16 h) {
  union { u32 u; float f; } v; v.u = ((u32)h) << 16; return v.f;
}

// ---------------- CSR count + x->bf16 convert (NE == NN*D/8 == 1.6M) -------
__global__ __launch_bounds__(256) void k_count_cvt(const int* __restrict__ dst,
    int* __restrict__ deg, const float* __restrict__ xin, u16* __restrict__ xb) {
  int e = blockIdx.x * 256 + threadIdx.x;
  if (e >= NE) return;
  atomicAdd(&deg[dst[e]], 1);
  const float4* p = reinterpret_cast<const float4*>(xin) + (size_t)e * 2;
  float4 a = p[0], b = p[1];
  u16x8 o;
  o[0] = f2b(a.x); o[1] = f2b(a.y); o[2] = f2b(a.z); o[3] = f2b(a.w);
  o[4] = f2b(b.x); o[5] = f2b(b.y); o[6] = f2b(b.z); o[7] = f2b(b.w);
  *reinterpret_cast<u16x8*>(xb + (size_t)e * 8) = o;
}

__global__ void k_scan1(const int* __restrict__ deg, int* __restrict__ incl,
                        int* __restrict__ bsum) {
  __shared__ int s[256];
  int t = threadIdx.x;
  int i = blockIdx.x * 256 + t;
  int v = (i < NN) ? deg[i] : 0;
  s[t] = v; __syncthreads();
  for (int off = 1; off < 256; off <<= 1) {
    int u = (t >= off) ? s[t - off] : 0;
    __syncthreads();
    s[t] += u; __syncthreads();
  }
  if (i < NN) incl[i] = s[t];
  if (t == 255) bsum[blockIdx.x] = s[255];
}

__global__ void k_scan2(int* __restrict__ bsum, int nb) {
  __shared__ int s[512];
  int t = threadIdx.x;
  int v = (t < nb) ? bsum[t] : 0;
  s[t] = v; __syncthreads();
  for (int off = 1; off < 512; off <<= 1) {
    int u = (t >= off) ? s[t - off] : 0;
    __syncthreads();
    s[t] += u; __syncthreads();
  }
  if (t < nb) bsum[t] = s[t] - v;  // exclusive block offsets
}

__global__ void k_scan3(const int* __restrict__ incl, const int* __restrict__ deg,
                        const int* __restrict__ bsum, int* __restrict__ rowstart) {
  int i = blockIdx.x * 256 + threadIdx.x;
  if (i < NN) {
    int ex = incl[i] - deg[i] + bsum[blockIdx.x];
    rowstart[i] = ex;
    if (i == NN - 1) rowstart[NN] = ex + deg[i];
  }
}

__global__ void k_fill(const int* __restrict__ src, const int* __restrict__ dst,
                       const int* __restrict__ rowstart, int* __restrict__ cursor,
                       int* __restrict__ col) {
  int e = blockIdx.x * blockDim.x + threadIdx.x;
  if (e < NE) {
    int d = dst[e];
    int p = atomicAdd(&cursor[d], 1);
    col[rowstart[d] + p] = src[e];
  }
}

// ---------------- W (k-major [k][n]) -> Wt (n-major [n][k]) bf16, 4 mats ----
__global__ void k_cvt_wt4(const float* __restrict__ W0, const float* __restrict__ W1,
                          const float* __restrict__ W2, const float* __restrict__ W3,
                          u16* __restrict__ T0, u16* __restrict__ T1,
                          u16* __restrict__ T2, u16* __restrict__ T3) {
  const float* W = blockIdx.y == 0 ? W0 : blockIdx.y == 1 ? W1 : blockIdx.y == 2 ? W2 : W3;
  u16* T = blockIdx.y == 0 ? T0 : blockIdx.y == 1 ? T1 : blockIdx.y == 2 ? T2 : T3;
  int n = blockIdx.x, k = threadIdx.x;
  T[n * D + k] = f2b(W[k * D + n]);
}

// ---------------- mean aggregation: quarter-wave per row, 8 gathers in flight
__global__ __launch_bounds__(256) void k_agg_b(const u16* __restrict__ feat,
    const int* __restrict__ rowstart, const int* __restrict__ col,
    u16* __restrict__ out) {
  int wid = threadIdx.x >> 6;
  int lane = threadIdx.x & 63;
  int node = blockIdx.x * 4 + wid;
  if (node >= NN) return;
  int b = rowstart[node], e = rowstart[node + 1];
  int q = lane >> 4;         // quarter 0..3 -> edge slot
  int fl = lane & 15;        // feature chunk: elems fl*8 .. fl*8+7
  float a[8] = {};
  int j = b + q;
  for (; j + 4 < e; j += 8) {   // two rows in flight per quarter
    int s0 = col[j], s1 = col[j + 4];
    u16x8 v0 = *reinterpret_cast<const u16x8*>(&feat[(size_t)s0 * D + fl * 8]);
    u16x8 v1 = *reinterpret_cast<const u16x8*>(&feat[(size_t)s1 * D + fl * 8]);
    #pragma unroll
    for (int t = 0; t < 8; ++t) a[t] += b2f(v0[t]) + b2f(v1[t]);
  }
  if (j < e) {
    int s0 = col[j];
    u16x8 v0 = *reinterpret_cast<const u16x8*>(&feat[(size_t)s0 * D + fl * 8]);
    #pragma unroll
    for (int t = 0; t < 8; ++t) a[t] += b2f(v0[t]);
  }
  #pragma unroll
  for (int t = 0; t < 8; ++t) {     // sum the 4 quarters
    a[t] += __shfl_xor(a[t], 16, 64);
    a[t] += __shfl_xor(a[t], 32, 64);
  }
  if (q == 0) {
    float inv = (e > b) ? 1.f / (float)(e - b) : 0.f;
    u16x8 o;
    #pragma unroll
    for (int t = 0; t < 8; ++t) o[t] = f2b(a[t] * inv);
    *reinterpret_cast<u16x8*>(&out[(size_t)node * D + fl * 8]) = o;
  }
}

// ---------------- fused dual GEMM via MFMA (layer 1): C = relu(A@Wt1^T + B@Wt2^T + b)
__global__ __launch_bounds__(256) void k_gemm_mfma(
    const u16* __restrict__ A, const u16* __restrict__ B,
    const u16* __restrict__ Wt1, const u16* __restrict__ Wt2,
    const float* __restrict__ bias, u16* __restrict__ Cout)
{
  int wid = threadIdx.x >> 6, lane = threadIdx.x & 63;
  int rbase = blockIdx.x * 64 + wid * 16;
  if (rbase >= NN) return;
  int l15 = lane & 15, g = lane >> 4;

  int frow = rbase + l15;
  if (frow >= NN) frow = NN - 1;
  size_t aoff = (size_t)frow * D + g * 8;

  f32x4 acc[8] = {};
  #pragma unroll
  for (int phase = 0; phase < 2; ++phase) {
    const u16* Act = phase ? B : A;
    const u16* Wt  = phase ? Wt2 : Wt1;
    #pragma unroll
    for (int kb = 0; kb < D; kb += 32) {
      bf16x8 af = *reinterpret_cast<const bf16x8*>(&Act[aoff + kb]);
      #pragma unroll
      for (int c = 0; c < 8; ++c) {
        bf16x8 wf = *reinterpret_cast<const bf16x8*>(&Wt[(size_t)(c * 16 + l15) * D + kb + g * 8]);
        acc[c] = __builtin_amdgcn_mfma_f32_16x16x32_bf16(af, wf, acc[c], 0, 0, 0);
      }
    }
  }
  #pragma unroll
  for (int c = 0; c < 8; ++c) {
    float bv = bias[c * 16 + l15];
    #pragma unroll
    for (int r = 0; r < 4; ++r) {
      int row = rbase + g * 4 + r;
      if (row < NN) {
        float v = fmaxf(acc[c][r] + bv, 0.f);
        Cout[(size_t)row * D + c * 16 + l15] = f2b(v);
      }
    }
  }
}

// ---------------- layer-2 GEMM + fused layer-3 projection -------------------
// z[row] = relu(h2)·Wl3 ; r[row] = relu(h2)·Wr3 + b3   (h2 never stored)
__global__ __launch_bounds__(256) void k_gemm2_zr(
    const u16* __restrict__ A, const u16* __restrict__ B,
    const u16* __restrict__ Wt1, const u16* __restrict__ Wt2,
    const float* __restrict__ bias,
    const float* __restrict__ Wl3, const float* __restrict__ Wr3,
    const float* __restrict__ b3,
    float* __restrict__ z, float* __restrict__ r)
{
  int wid = threadIdx.x >> 6, lane = threadIdx.x & 63;
  int rbase = blockIdx.x * 64 + wid * 16;
  if (rbase >= NN) return;
  int l15 = lane & 15, g = lane >> 4;

  int frow = rbase + l15;
  if (frow >= NN) frow = NN - 1;
  size_t aoff = (size_t)frow * D + g * 8;

  f32x4 acc[8] = {};
  #pragma unroll
  for (int phase = 0; phase < 2; ++phase) {
    const u16* Act = phase ? B : A;
    const u16* Wt  = phase ? Wt2 : Wt1;
    #pragma unroll
    for (int kb = 0; kb < D; kb += 32) {
      bf16x8 af = *reinterpret_cast<const bf16x8*>(&Act[aoff + kb]);
      #pragma unroll
      for (int c = 0; c < 8; ++c) {
        bf16x8 wf = *reinterpret_cast<const bf16x8*>(&Wt[(size_t)(c * 16 + l15) * D + kb + g * 8]);
        acc[c] = __builtin_amdgcn_mfma_f32_16x16x32_bf16(af, wf, acc[c], 0, 0, 0);
      }
    }
  }
  float wl[8], wr[8], bv[8];
  #pragma unroll
  for (int c = 0; c < 8; ++c) {
    wl[c] = Wl3[c * 16 + l15];
    wr[c] = Wr3[c * 16 + l15];
    bv[c] = bias[c * 16 + l15];
  }
  float bb3 = b3[0];
  #pragma unroll
  for (int rr = 0; rr < 4; ++rr) {
    float pz = 0.f, pr = 0.f;
    #pragma unroll
    for (int c = 0; c < 8; ++c) {
      float v = fmaxf(acc[c][rr] + bv[c], 0.f);
      pz += v * wl[c];
      pr += v * wr[c];
    }
    pz += __shfl_xor(pz, 1, 64); pr += __shfl_xor(pr, 1, 64);
    pz += __shfl_xor(pz, 2, 64); pr += __shfl_xor(pr, 2, 64);
    pz += __shfl_xor(pz, 4, 64); pr += __shfl_xor(pr, 4, 64);
    pz += __shfl_xor(pz, 8, 64); pr += __shfl_xor(pr, 8, 64);
    int row = rbase + g * 4 + rr;
    if (l15 == 0 && row < NN) {
      z[row] = pz;
      r[row] = pr + bb3;
    }
  }
}

// ---------------- final: out = r + mean(z over neighbors), 16 lanes/node ----
__global__ __launch_bounds__(256) void k_out(const float* __restrict__ z,
    const float* __restrict__ r, const int* __restrict__ rowstart,
    const int* __restrict__ col, float* __restrict__ out) {
  int t = threadIdx.x;
  int sub = t & 15;
  int node = blockIdx.x * 16 + (t >> 4);
  if (node >= NN) return;
  int b = rowstart[node], e = rowstart[node + 1];
  float s = 0.f;
  for (int j = b + sub; j < e; j += 16) s += z[col[j]];
  s += __shfl_xor(s, 1, 64);
  s += __shfl_xor(s, 2, 64);
  s += __shfl_xor(s, 4, 64);
  s += __shfl_xor(s, 8, 64);
  if (sub == 0) {
    float inv = (e > b) ? 1.f / (float)(e - b) : 0.f;
    out[node] = r[node] + s * inv;
  }
}

extern "C" void kernel_launch(void* const* d_in, const int* in_sizes, int n_in,
                              void* d_out, int out_size, void* d_ws, size_t ws_size,
                              hipStream_t stream) {
  const float* x   = (const float*)d_in[0];
  const int*   ei  = (const int*)d_in[1];
  const float* Wl1 = (const float*)d_in[2];
  const float* Wr1 = (const float*)d_in[3];
  const float* b1  = (const float*)d_in[4];
  const float* Wl2 = (const float*)d_in[5];
  const float* Wr2 = (const float*)d_in[6];
  const float* b2  = (const float*)d_in[7];
  const float* Wl3 = (const float*)d_in[8];
  const float* Wr3 = (const float*)d_in[9];
  const float* b3  = (const float*)d_in[10];
  const int* srcv = ei;
  const int* dstv = ei + NE;
  float* out = (float*)d_out;

  char* ws = (char*)d_ws;
  size_t off = 0;
  auto alloc = [&](size_t bytes) {
    size_t o = off;
    off += (bytes + 255) & ~(size_t)255;
    return o;
  };
  int* deg      = (int*)(ws + alloc((size_t)2 * NN * 4)); // deg + cursor contiguous
  int* cursor   = deg + NN;
  int* incl     = (int*)(ws + alloc((size_t)NN * 4));
  int* rowstart = (int*)(ws + alloc((size_t)(NN + 1) * 4));
  int* col      = (int*)(ws + alloc((size_t)NE * 4));
  int* bsum     = (int*)(ws + alloc(512 * 4));
  u16* xb   = (u16*)(ws + alloc((size_t)NN * D * 2));
  u16* Ab   = (u16*)(ws + alloc((size_t)NN * D * 2));
  u16* H1b  = (u16*)(ws + alloc((size_t)NN * D * 2));
  u16* Wt1l = (u16*)(ws + alloc((size_t)D * D * 2));
  u16* Wt1r = (u16*)(ws + alloc((size_t)D * D * 2));
  u16* Wt2l = (u16*)(ws + alloc((size_t)D * D * 2));
  u16* Wt2r = (u16*)(ws + alloc((size_t)D * D * 2));
  float* z  = (float*)(ws + alloc((size_t)NN * 4));
  float* r  = (float*)(ws + alloc((size_t)NN * 4));

  const int nb_nodes = (NN + 255) / 256;     // 391
  const int nb_edges = (NE + 255) / 256;     // 6250
  const int nb_gemm  = (NN + 63) / 64;       // 1563
  const int nb_wave4 = (NN + 3) / 4;         // 25000
  const int nb_out   = (NN + 15) / 16;       // 6250

  hipMemsetAsync(deg, 0, (size_t)2 * NN * 4, stream);

  // CSR build (+ x -> bf16 fused into count pass)
  k_count_cvt<<<nb_edges, 256, 0, stream>>>(dstv, deg, x, xb);
  k_scan1<<<nb_nodes, 256, 0, stream>>>(deg, incl, bsum);
  k_scan2<<<1, 512, 0, stream>>>(bsum, nb_nodes);
  k_scan3<<<nb_nodes, 256, 0, stream>>>(incl, deg, bsum, rowstart);
  k_fill<<<nb_edges, 256, 0, stream>>>(srcv, dstv, rowstart, cursor, col);

  // weight prep (transposed bf16)
  k_cvt_wt4<<<dim3(D, 4), D, 0, stream>>>(Wl1, Wr1, Wl2, Wr2, Wt1l, Wt1r, Wt2l, Wt2r);

  // layer 1
  k_agg_b<<<nb_wave4, 256, 0, stream>>>(xb, rowstart, col, Ab);
  k_gemm_mfma<<<nb_gemm, 256, 0, stream>>>(Ab, xb, Wt1l, Wt1r, b1, H1b);
  // layer 2 + fused layer-3 projection
  k_agg_b<<<nb_wave4, 256, 0, stream>>>(H1b, rowstart, col, Ab);
  k_gemm2_zr<<<nb_gemm, 256, 0, stream>>>(Ab, H1b, Wt2l, Wt2r, b2, Wl3, Wr3, b3, z, r);
  // final
  k_out<<<nb_out, 256, 0, stream>>>(z, r, rowstart, col, out);
}

// Round 4
// 417.895 us; speedup vs baseline: 1.7186x; 1.0743x over previous
//
#include <hip/hip_runtime.h>
#include <hip/hip_bf16.h>

#define NN 100000
#define NE 1600000
#define D 128
#define NGRP 8
#define GSZ (NN / NGRP)        // 12500, exact
#define FILL_CHUNK 2048        // edges per fill block

typedef unsigned short u16;
typedef unsigned int u32;
typedef __attribute__((ext_vector_type(8))) short bf16x8;
typedef __attribute__((ext_vector_type(4))) float f32x4;
typedef __attribute__((ext_vector_type(8))) u16 u16x8;

__device__ inline u16 f2b(float f) {
  union { float f; u32 u; } v; v.f = f;
  u32 u = v.u;
  return (u16)((u + 0x7fffu + ((u >> 16) & 1u)) >> 16);
}
__device__ inline float b2f(u16 h) {
  union { u32 u; float f; } v; v.u = ((u32)h) << 16; return v.f;
}

// ---------------- CSR count + x->bf16 convert (NE == NN*D/8 == 1.6M) -------
__global__ __launch_bounds__(256) void k_count_cvt(const int* __restrict__ dst,
    int* __restrict__ deg, const float* __restrict__ xin, u16* __restrict__ xb) {
  int e = blockIdx.x * 256 + threadIdx.x;
  if (e >= NE) return;
  atomicAdd(&deg[dst[e]], 1);
  const float4* p = reinterpret_cast<const float4*>(xin) + (size_t)e * 2;
  float4 a = p[0], b = p[1];
  u16x8 o;
  o[0] = f2b(a.x); o[1] = f2b(a.y); o[2] = f2b(a.z); o[3] = f2b(a.w);
  o[4] = f2b(b.x); o[5] = f2b(b.y); o[6] = f2b(b.z); o[7] = f2b(b.w);
  *reinterpret_cast<u16x8*>(xb + (size_t)e * 8) = o;
}

__global__ void k_scan1(const int* __restrict__ deg, int* __restrict__ incl,
                        int* __restrict__ bsum) {
  __shared__ int s[256];
  int t = threadIdx.x;
  int i = blockIdx.x * 256 + t;
  int v = (i < NN) ? deg[i] : 0;
  s[t] = v; __syncthreads();
  for (int off = 1; off < 256; off <<= 1) {
    int u = (t >= off) ? s[t - off] : 0;
    __syncthreads();
    s[t] += u; __syncthreads();
  }
  if (i < NN) incl[i] = s[t];
  if (t == 255) bsum[blockIdx.x] = s[255];
}

__global__ void k_scan2(int* __restrict__ bsum, int nb) {
  __shared__ int s[512];
  int t = threadIdx.x;
  int v = (t < nb) ? bsum[t] : 0;
  s[t] = v; __syncthreads();
  for (int off = 1; off < 512; off <<= 1) {
    int u = (t >= off) ? s[t - off] : 0;
    __syncthreads();
    s[t] += u; __syncthreads();
  }
  if (t < nb) bsum[t] = s[t] - v;  // exclusive block offsets
}

__global__ void k_scan3(const int* __restrict__ incl, const int* __restrict__ deg,
                        const int* __restrict__ bsum, int* __restrict__ rowstart) {
  int i = blockIdx.x * 256 + threadIdx.x;
  if (i < NN) {
    int ex = incl[i] - deg[i] + bsum[blockIdx.x];
    rowstart[i] = ex;
    if (i == NN - 1) rowstart[NN] = ex + deg[i];
  }
}

// ---------------- fill, XCD-ownership partitioned ---------------------------
// group g = blockIdx.x & 7 owns dst in [g*GSZ, (g+1)*GSZ): its col writes land
// in one contiguous ~800KB slice that stays resident in that XCD's L2 until
// lines are fully populated (kills the 16x write amplification).
__global__ __launch_bounds__(256) void k_fill(const int* __restrict__ src,
    const int* __restrict__ dst, const int* __restrict__ rowstart,
    int* __restrict__ cursor, int* __restrict__ col) {
  int grp = blockIdx.x & (NGRP - 1);
  int base = (blockIdx.x >> 3) * FILL_CHUNK;
  int lo = grp * GSZ, hi = lo + GSZ;
  #pragma unroll
  for (int i = 0; i < FILL_CHUNK; i += 256) {
    int e = base + i + threadIdx.x;
    if (e < NE) {
      int d = dst[e];
      if (d >= lo && d < hi) {
        int p = atomicAdd(&cursor[d], 1);
        col[rowstart[d] + p] = src[e];
      }
    }
  }
}

// ---------------- W (k-major [k][n]) -> Wt (n-major [n][k]) bf16, 4 mats ----
__global__ void k_cvt_wt4(const float* __restrict__ W0, const float* __restrict__ W1,
                          const float* __restrict__ W2, const float* __restrict__ W3,
                          u16* __restrict__ T0, u16* __restrict__ T1,
                          u16* __restrict__ T2, u16* __restrict__ T3) {
  const float* W = blockIdx.y == 0 ? W0 : blockIdx.y == 1 ? W1 : blockIdx.y == 2 ? W2 : W3;
  u16* T = blockIdx.y == 0 ? T0 : blockIdx.y == 1 ? T1 : blockIdx.y == 2 ? T2 : T3;
  int n = blockIdx.x, k = threadIdx.x;
  T[n * D + k] = f2b(W[k * D + n]);
}

// ---------------- mean aggregation: quarter-wave per row, 16 gathers in flight
__global__ __launch_bounds__(256) void k_agg_b(const u16* __restrict__ feat,
    const int* __restrict__ rowstart, const int* __restrict__ col,
    u16* __restrict__ out) {
  int wid = threadIdx.x >> 6;
  int lane = threadIdx.x & 63;
  int node = blockIdx.x * 4 + wid;
  if (node >= NN) return;
  int b = rowstart[node], e = rowstart[node + 1];
  int q = lane >> 4;         // quarter 0..3 -> edge slot
  int fl = lane & 15;        // feature chunk: elems fl*8 .. fl*8+7
  float a[8] = {};
  int j = b + q;
  for (; j + 12 < e; j += 16) {   // four rows in flight per quarter
    int s0 = col[j], s1 = col[j + 4], s2 = col[j + 8], s3 = col[j + 12];
    u16x8 v0 = *reinterpret_cast<const u16x8*>(&feat[(size_t)s0 * D + fl * 8]);
    u16x8 v1 = *reinterpret_cast<const u16x8*>(&feat[(size_t)s1 * D + fl * 8]);
    u16x8 v2 = *reinterpret_cast<const u16x8*>(&feat[(size_t)s2 * D + fl * 8]);
    u16x8 v3 = *reinterpret_cast<const u16x8*>(&feat[(size_t)s3 * D + fl * 8]);
    #pragma unroll
    for (int t = 0; t < 8; ++t)
      a[t] += (b2f(v0[t]) + b2f(v1[t])) + (b2f(v2[t]) + b2f(v3[t]));
  }
  for (; j < e; j += 4) {
    int s0 = col[j];
    u16x8 v0 = *reinterpret_cast<const u16x8*>(&feat[(size_t)s0 * D + fl * 8]);
    #pragma unroll
    for (int t = 0; t < 8; ++t) a[t] += b2f(v0[t]);
  }
  #pragma unroll
  for (int t = 0; t < 8; ++t) {     // sum the 4 quarters
    a[t] += __shfl_xor(a[t], 16, 64);
    a[t] += __shfl_xor(a[t], 32, 64);
  }
  if (q == 0) {
    float inv = (e > b) ? 1.f / (float)(e - b) : 0.f;
    u16x8 o;
    #pragma unroll
    for (int t = 0; t < 8; ++t) o[t] = f2b(a[t] * inv);
    *reinterpret_cast<u16x8*>(&out[(size_t)node * D + fl * 8]) = o;
  }
}

// ---------------- fused dual GEMM via MFMA (layer 1): C = relu(A@Wt1^T + B@Wt2^T + b)
__global__ __launch_bounds__(256) void k_gemm_mfma(
    const u16* __restrict__ A, const u16* __restrict__ B,
    const u16* __restrict__ Wt1, const u16* __restrict__ Wt2,
    const float* __restrict__ bias, u16* __restrict__ Cout)
{
  int wid = threadIdx.x >> 6, lane = threadIdx.x & 63;
  int rbase = blockIdx.x * 64 + wid * 16;
  if (rbase >= NN) return;
  int l15 = lane & 15, g = lane >> 4;

  int frow = rbase + l15;
  if (frow >= NN) frow = NN - 1;
  size_t aoff = (size_t)frow * D + g * 8;

  f32x4 acc[8] = {};
  #pragma unroll
  for (int phase = 0; phase < 2; ++phase) {
    const u16* Act = phase ? B : A;
    const u16* Wt  = phase ? Wt2 : Wt1;
    #pragma unroll
    for (int kb = 0; kb < D; kb += 32) {
      bf16x8 af = *reinterpret_cast<const bf16x8*>(&Act[aoff + kb]);
      #pragma unroll
      for (int c = 0; c < 8; ++c) {
        bf16x8 wf = *reinterpret_cast<const bf16x8*>(&Wt[(size_t)(c * 16 + l15) * D + kb + g * 8]);
        acc[c] = __builtin_amdgcn_mfma_f32_16x16x32_bf16(af, wf, acc[c], 0, 0, 0);
      }
    }
  }
  #pragma unroll
  for (int c = 0; c < 8; ++c) {
    float bv = bias[c * 16 + l15];
    #pragma unroll
    for (int r = 0; r < 4; ++r) {
      int row = rbase + g * 4 + r;
      if (row < NN) {
        float v = fmaxf(acc[c][r] + bv, 0.f);
        Cout[(size_t)row * D + c * 16 + l15] = f2b(v);
      }
    }
  }
}

// ---------------- layer-2 GEMM + fused layer-3 projection -------------------
// z[row] = relu(h2)·Wl3 ; r[row] = relu(h2)·Wr3 + b3   (h2 never stored)
__global__ __launch_bounds__(256) void k_gemm2_zr(
    const u16* __restrict__ A, const u16* __restrict__ B,
    const u16* __restrict__ Wt1, const u16* __restrict__ Wt2,
    const float* __restrict__ bias,
    const float* __restrict__ Wl3, const float* __restrict__ Wr3,
    const float* __restrict__ b3,
    float* __restrict__ z, float* __restrict__ r)
{
  int wid = threadIdx.x >> 6, lane = threadIdx.x & 63;
  int rbase = blockIdx.x * 64 + wid * 16;
  if (rbase >= NN) return;
  int l15 = lane & 15, g = lane >> 4;

  int frow = rbase + l15;
  if (frow >= NN) frow = NN - 1;
  size_t aoff = (size_t)frow * D + g * 8;

  f32x4 acc[8] = {};
  #pragma unroll
  for (int phase = 0; phase < 2; ++phase) {
    const u16* Act = phase ? B : A;
    const u16* Wt  = phase ? Wt2 : Wt1;
    #pragma unroll
    for (int kb = 0; kb < D; kb += 32) {
      bf16x8 af = *reinterpret_cast<const bf16x8*>(&Act[aoff + kb]);
      #pragma unroll
      for (int c = 0; c < 8; ++c) {
        bf16x8 wf = *reinterpret_cast<const bf16x8*>(&Wt[(size_t)(c * 16 + l15) * D + kb + g * 8]);
        acc[c] = __builtin_amdgcn_mfma_f32_16x16x32_bf16(af, wf, acc[c], 0, 0, 0);
      }
    }
  }
  float wl[8], wr[8], bv[8];
  #pragma unroll
  for (int c = 0; c < 8; ++c) {
    wl[c] = Wl3[c * 16 + l15];
    wr[c] = Wr3[c * 16 + l15];
    bv[c] = bias[c * 16 + l15];
  }
  float bb3 = b3[0];
  #pragma unroll
  for (int rr = 0; rr < 4; ++rr) {
    float pz = 0.f, pr = 0.f;
    #pragma unroll
    for (int c = 0; c < 8; ++c) {
      float v = fmaxf(acc[c][rr] + bv[c], 0.f);
      pz += v * wl[c];
      pr += v * wr[c];
    }
    pz += __shfl_xor(pz, 1, 64); pr += __shfl_xor(pr, 1, 64);
    pz += __shfl_xor(pz, 2, 64); pr += __shfl_xor(pr, 2, 64);
    pz += __shfl_xor(pz, 4, 64); pr += __shfl_xor(pr, 4, 64);
    pz += __shfl_xor(pz, 8, 64); pr += __shfl_xor(pr, 8, 64);
    int row = rbase + g * 4 + rr;
    if (l15 == 0 && row < NN) {
      z[row] = pz;
      r[row] = pr + bb3;
    }
  }
}

// ---------------- final: out = r + mean(z over neighbors), 16 lanes/node ----
__global__ __launch_bounds__(256) void k_out(const float* __restrict__ z,
    const float* __restrict__ r, const int* __restrict__ rowstart,
    const int* __restrict__ col, float* __restrict__ out) {
  int t = threadIdx.x;
  int sub = t & 15;
  int node = blockIdx.x * 16 + (t >> 4);
  if (node >= NN) return;
  int b = rowstart[node], e = rowstart[node + 1];
  float s = 0.f;
  for (int j = b + sub; j < e; j += 16) s += z[col[j]];
  s += __shfl_xor(s, 1, 64);
  s += __shfl_xor(s, 2, 64);
  s += __shfl_xor(s, 4, 64);
  s += __shfl_xor(s, 8, 64);
  if (sub == 0) {
    float inv = (e > b) ? 1.f / (float)(e - b) : 0.f;
    out[node] = r[node] + s * inv;
  }
}

extern "C" void kernel_launch(void* const* d_in, const int* in_sizes, int n_in,
                              void* d_out, int out_size, void* d_ws, size_t ws_size,
                              hipStream_t stream) {
  const float* x   = (const float*)d_in[0];
  const int*   ei  = (const int*)d_in[1];
  const float* Wl1 = (const float*)d_in[2];
  const float* Wr1 = (const float*)d_in[3];
  const float* b1  = (const float*)d_in[4];
  const float* Wl2 = (const float*)d_in[5];
  const float* Wr2 = (const float*)d_in[6];
  const float* b2  = (const float*)d_in[7];
  const float* Wl3 = (const float*)d_in[8];
  const float* Wr3 = (const float*)d_in[9];
  const float* b3  = (const float*)d_in[10];
  const int* srcv = ei;
  const int* dstv = ei + NE;
  float* out = (float*)d_out;

  char* ws = (char*)d_ws;
  size_t off = 0;
  auto alloc = [&](size_t bytes) {
    size_t o = off;
    off += (bytes + 255) & ~(size_t)255;
    return o;
  };
  int* deg      = (int*)(ws + alloc((size_t)2 * NN * 4)); // deg + cursor contiguous
  int* cursor   = deg + NN;
  int* incl     = (int*)(ws + alloc((size_t)NN * 4));
  int* rowstart = (int*)(ws + alloc((size_t)(NN + 1) * 4));
  int* col      = (int*)(ws + alloc((size_t)NE * 4));
  int* bsum     = (int*)(ws + alloc(512 * 4));
  u16* xb   = (u16*)(ws + alloc((size_t)NN * D * 2));
  u16* Ab   = (u16*)(ws + alloc((size_t)NN * D * 2));
  u16* H1b  = (u16*)(ws + alloc((size_t)NN * D * 2));
  u16* Wt1l = (u16*)(ws + alloc((size_t)D * D * 2));
  u16* Wt1r = (u16*)(ws + alloc((size_t)D * D * 2));
  u16* Wt2l = (u16*)(ws + alloc((size_t)D * D * 2));
  u16* Wt2r = (u16*)(ws + alloc((size_t)D * D * 2));
  float* z  = (float*)(ws + alloc((size_t)NN * 4));
  float* r  = (float*)(ws + alloc((size_t)NN * 4));

  const int nb_nodes = (NN + 255) / 256;     // 391
  const int nb_edges = (NE + 255) / 256;     // 6250
  const int nb_gemm  = (NN + 63) / 64;       // 1563
  const int nb_wave4 = (NN + 3) / 4;         // 25000
  const int nb_out   = (NN + 15) / 16;       // 6250
  const int nb_fill  = NGRP * ((NE + FILL_CHUNK - 1) / FILL_CHUNK);  // 8*782

  hipMemsetAsync(deg, 0, (size_t)2 * NN * 4, stream);

  // CSR build (+ x -> bf16 fused into count pass)
  k_count_cvt<<<nb_edges, 256, 0, stream>>>(dstv, deg, x, xb);
  k_scan1<<<nb_nodes, 256, 0, stream>>>(deg, incl, bsum);
  k_scan2<<<1, 512, 0, stream>>>(bsum, nb_nodes);
  k_scan3<<<nb_nodes, 256, 0, stream>>>(incl, deg, bsum, rowstart);
  k_fill<<<nb_fill, 256, 0, stream>>>(srcv, dstv, rowstart, cursor, col);

  // weight prep (transposed bf16)
  k_cvt_wt4<<<dim3(D, 4), D, 0, stream>>>(Wl1, Wr1, Wl2, Wr2, Wt1l, Wt1r, Wt2l, Wt2r);

  // layer 1
  k_agg_b<<<nb_wave4, 256, 0, stream>>>(xb, rowstart, col, Ab);
  k_gemm_mfma<<<nb_gemm, 256, 0, stream>>>(Ab, xb, Wt1l, Wt1r, b1, H1b);
  // layer 2 + fused layer-3 projection
  k_agg_b<<<nb_wave4, 256, 0, stream>>>(H1b, rowstart, col, Ab);
  k_gemm2_zr<<<nb_gemm, 256, 0, stream>>>(Ab, H1b, Wt2l, Wt2r, b2, Wl3, Wr3, b3, z, r);
  // final
  k_out<<<nb_out, 256, 0, stream>>>(z, r, rowstart, col, out);
}

// Round 5
// 350.072 us; speedup vs baseline: 2.0516x; 1.1937x over previous
//
#include <hip/hip_runtime.h>
#include <hip/hip_bf16.h>

#define NN 100000
#define NE 1600000
#define D 128
#define NGRP 8
#define GSZ (NN / NGRP)        // 12500, exact
#define FILL_CHUNK 2048        // edges per fill block
#define WSTRIDE 136            // LDS row stride (u16 elems): 272B -> conflict-free b128

typedef unsigned short u16;
typedef unsigned int u32;
typedef __attribute__((ext_vector_type(8))) short bf16x8;
typedef __attribute__((ext_vector_type(4))) float f32x4;
typedef __attribute__((ext_vector_type(8))) u16 u16x8;

__device__ inline u16 f2b(float f) {
  union { float f; u32 u; } v; v.f = f;
  u32 u = v.u;
  return (u16)((u + 0x7fffu + ((u >> 16) & 1u)) >> 16);
}
__device__ inline float b2f(u16 h) {
  union { u32 u; float f; } v; v.u = ((u32)h) << 16; return v.f;
}

// ---------------- CSR count + x->bf16 convert (NE == NN*D/8 == 1.6M) -------
__global__ __launch_bounds__(256) void k_count_cvt(const int* __restrict__ dst,
    int* __restrict__ deg, const float* __restrict__ xin, u16* __restrict__ xb) {
  int e = blockIdx.x * 256 + threadIdx.x;
  if (e >= NE) return;
  atomicAdd(&deg[dst[e]], 1);
  const float4* p = reinterpret_cast<const float4*>(xin) + (size_t)e * 2;
  float4 a = p[0], b = p[1];
  u16x8 o;
  o[0] = f2b(a.x); o[1] = f2b(a.y); o[2] = f2b(a.z); o[3] = f2b(a.w);
  o[4] = f2b(b.x); o[5] = f2b(b.y); o[6] = f2b(b.z); o[7] = f2b(b.w);
  *reinterpret_cast<u16x8*>(xb + (size_t)e * 8) = o;
}

__global__ void k_scan1(const int* __restrict__ deg, int* __restrict__ incl,
                        int* __restrict__ bsum) {
  __shared__ int s[256];
  int t = threadIdx.x;
  int i = blockIdx.x * 256 + t;
  int v = (i < NN) ? deg[i] : 0;
  s[t] = v; __syncthreads();
  for (int off = 1; off < 256; off <<= 1) {
    int u = (t >= off) ? s[t - off] : 0;
    __syncthreads();
    s[t] += u; __syncthreads();
  }
  if (i < NN) incl[i] = s[t];
  if (t == 255) bsum[blockIdx.x] = s[255];
}

__global__ void k_scan2(int* __restrict__ bsum, int nb) {
  __shared__ int s[512];
  int t = threadIdx.x;
  int v = (t < nb) ? bsum[t] : 0;
  s[t] = v; __syncthreads();
  for (int off = 1; off < 512; off <<= 1) {
    int u = (t >= off) ? s[t - off] : 0;
    __syncthreads();
    s[t] += u; __syncthreads();
  }
  if (t < nb) bsum[t] = s[t] - v;  // exclusive block offsets
}

__global__ void k_scan3(const int* __restrict__ incl, const int* __restrict__ deg,
                        const int* __restrict__ bsum, int* __restrict__ rowstart) {
  int i = blockIdx.x * 256 + threadIdx.x;
  if (i < NN) {
    int ex = incl[i] - deg[i] + bsum[blockIdx.x];
    rowstart[i] = ex;
    if (i == NN - 1) rowstart[NN] = ex + deg[i];
  }
}

// ---------------- fill, XCD-ownership partitioned ---------------------------
__global__ __launch_bounds__(256) void k_fill(const int* __restrict__ src,
    const int* __restrict__ dst, const int* __restrict__ rowstart,
    int* __restrict__ cursor, int* __restrict__ col) {
  int grp = blockIdx.x & (NGRP - 1);
  int base = (blockIdx.x >> 3) * FILL_CHUNK;
  int lo = grp * GSZ, hi = lo + GSZ;
  #pragma unroll
  for (int i = 0; i < FILL_CHUNK; i += 256) {
    int e = base + i + threadIdx.x;
    if (e < NE) {
      int d = dst[e];
      if (d >= lo && d < hi) {
        int p = atomicAdd(&cursor[d], 1);
        col[rowstart[d] + p] = src[e];
      }
    }
  }
}

// ---------------- W (k-major [k][n]) -> Wt (n-major [n][k]) bf16, 4 mats ----
__global__ void k_cvt_wt4(const float* __restrict__ W0, const float* __restrict__ W1,
                          const float* __restrict__ W2, const float* __restrict__ W3,
                          u16* __restrict__ T0, u16* __restrict__ T1,
                          u16* __restrict__ T2, u16* __restrict__ T3) {
  const float* W = blockIdx.y == 0 ? W0 : blockIdx.y == 1 ? W1 : blockIdx.y == 2 ? W2 : W3;
  u16* T = blockIdx.y == 0 ? T0 : blockIdx.y == 1 ? T1 : blockIdx.y == 2 ? T2 : T3;
  int n = blockIdx.x, k = threadIdx.x;
  T[n * D + k] = f2b(W[k * D + n]);
}

// ---------------- mean aggregation: quarter-wave per row, 16 gathers in flight
__global__ __launch_bounds__(256) void k_agg_b(const u16* __restrict__ feat,
    const int* __restrict__ rowstart, const int* __restrict__ col,
    u16* __restrict__ out) {
  int wid = threadIdx.x >> 6;
  int lane = threadIdx.x & 63;
  int node = blockIdx.x * 4 + wid;
  if (node >= NN) return;
  int b = rowstart[node], e = rowstart[node + 1];
  int q = lane >> 4;         // quarter 0..3 -> edge slot
  int fl = lane & 15;        // feature chunk: elems fl*8 .. fl*8+7
  float a[8] = {};
  int j = b + q;
  for (; j + 12 < e; j += 16) {   // four rows in flight per quarter
    int s0 = col[j], s1 = col[j + 4], s2 = col[j + 8], s3 = col[j + 12];
    u16x8 v0 = *reinterpret_cast<const u16x8*>(&feat[(size_t)s0 * D + fl * 8]);
    u16x8 v1 = *reinterpret_cast<const u16x8*>(&feat[(size_t)s1 * D + fl * 8]);
    u16x8 v2 = *reinterpret_cast<const u16x8*>(&feat[(size_t)s2 * D + fl * 8]);
    u16x8 v3 = *reinterpret_cast<const u16x8*>(&feat[(size_t)s3 * D + fl * 8]);
    #pragma unroll
    for (int t = 0; t < 8; ++t)
      a[t] += (b2f(v0[t]) + b2f(v1[t])) + (b2f(v2[t]) + b2f(v3[t]));
  }
  for (; j < e; j += 4) {
    int s0 = col[j];
    u16x8 v0 = *reinterpret_cast<const u16x8*>(&feat[(size_t)s0 * D + fl * 8]);
    #pragma unroll
    for (int t = 0; t < 8; ++t) a[t] += b2f(v0[t]);
  }
  #pragma unroll
  for (int t = 0; t < 8; ++t) {     // sum the 4 quarters
    a[t] += __shfl_xor(a[t], 16, 64);
    a[t] += __shfl_xor(a[t], 32, 64);
  }
  if (q == 0) {
    float inv = (e > b) ? 1.f / (float)(e - b) : 0.f;
    u16x8 o;
    #pragma unroll
    for (int t = 0; t < 8; ++t) o[t] = f2b(a[t] * inv);
    *reinterpret_cast<u16x8*>(&out[(size_t)node * D + fl * 8]) = o;
  }
}

// ---------------- fused dual GEMM via MFMA, weights staged in LDS -----------
// block = 128 rows, 4 waves x 32 rows (2 row-frags); weights Wt (n-major) in
// LDS with padded stride (272B) -> conflict-free ds_read_b128; one matrix
// staged per phase (34.8KB LDS -> 4 blocks/CU).
__global__ __launch_bounds__(256) void k_gemm_mfma(
    const u16* __restrict__ A, const u16* __restrict__ B,
    const u16* __restrict__ Wt1, const u16* __restrict__ Wt2,
    const float* __restrict__ bias, u16* __restrict__ Cout)
{
  __shared__ u16 wlds[128 * WSTRIDE];
  const int t = threadIdx.x;
  const int wid = t >> 6, lane = t & 63;
  const int l15 = lane & 15, g = lane >> 4;
  const int rbase = blockIdx.x * 128 + wid * 32;

  int r0 = rbase + l15, r1 = r0 + 16;
  size_t a0 = (size_t)(r0 < NN ? r0 : NN - 1) * D + g * 8;
  size_t a1 = (size_t)(r1 < NN ? r1 : NN - 1) * D + g * 8;

  f32x4 acc0[8] = {}, acc1[8] = {};

  #pragma unroll
  for (int phase = 0; phase < 2; ++phase) {
    const u16* Act = phase ? B : A;
    const u16* Wt  = phase ? Wt2 : Wt1;
    // stage weight matrix (n-major 128x128) into LDS, padded stride
    #pragma unroll
    for (int q = 0; q < 8; ++q) {
      int i = q * 256 + t;           // 16B chunk id, 2048 total
      int n = i >> 4, kc = i & 15;
      *reinterpret_cast<u16x8*>(&wlds[n * WSTRIDE + kc * 8]) =
          *reinterpret_cast<const u16x8*>(&Wt[n * D + kc * 8]);
    }
    __syncthreads();
    #pragma unroll
    for (int kb = 0; kb < 4; ++kb) {
      bf16x8 af0 = *reinterpret_cast<const bf16x8*>(&Act[a0 + kb * 32]);
      bf16x8 af1 = *reinterpret_cast<const bf16x8*>(&Act[a1 + kb * 32]);
      #pragma unroll
      for (int c = 0; c < 8; ++c) {
        bf16x8 wf = *reinterpret_cast<const bf16x8*>(
            &wlds[(c * 16 + l15) * WSTRIDE + kb * 32 + g * 8]);
        acc0[c] = __builtin_amdgcn_mfma_f32_16x16x32_bf16(af0, wf, acc0[c], 0, 0, 0);
        acc1[c] = __builtin_amdgcn_mfma_f32_16x16x32_bf16(af1, wf, acc1[c], 0, 0, 0);
      }
    }
    __syncthreads();   // all waves done reading before restage
  }

  #pragma unroll
  for (int c = 0; c < 8; ++c) {
    float bv = bias[c * 16 + l15];
    #pragma unroll
    for (int r = 0; r < 4; ++r) {
      int row0 = rbase + g * 4 + r;
      if (row0 < NN) {
        float v = fmaxf(acc0[c][r] + bv, 0.f);
        Cout[(size_t)row0 * D + c * 16 + l15] = f2b(v);
      }
      int row1 = row0 + 16;
      if (row1 < NN) {
        float v = fmaxf(acc1[c][r] + bv, 0.f);
        Cout[(size_t)row1 * D + c * 16 + l15] = f2b(v);
      }
    }
  }
}

// ---------------- layer-2 GEMM (LDS weights) + fused layer-3 projection -----
__global__ __launch_bounds__(256) void k_gemm2_zr(
    const u16* __restrict__ A, const u16* __restrict__ B,
    const u16* __restrict__ Wt1, const u16* __restrict__ Wt2,
    const float* __restrict__ bias,
    const float* __restrict__ Wl3, const float* __restrict__ Wr3,
    const float* __restrict__ b3,
    float* __restrict__ z, float* __restrict__ r)
{
  __shared__ u16 wlds[128 * WSTRIDE];
  const int t = threadIdx.x;
  const int wid = t >> 6, lane = t & 63;
  const int l15 = lane & 15, g = lane >> 4;
  const int rbase = blockIdx.x * 128 + wid * 32;

  int r0 = rbase + l15, r1 = r0 + 16;
  size_t a0 = (size_t)(r0 < NN ? r0 : NN - 1) * D + g * 8;
  size_t a1 = (size_t)(r1 < NN ? r1 : NN - 1) * D + g * 8;

  f32x4 acc0[8] = {}, acc1[8] = {};

  #pragma unroll
  for (int phase = 0; phase < 2; ++phase) {
    const u16* Act = phase ? B : A;
    const u16* Wt  = phase ? Wt2 : Wt1;
    #pragma unroll
    for (int q = 0; q < 8; ++q) {
      int i = q * 256 + t;
      int n = i >> 4, kc = i & 15;
      *reinterpret_cast<u16x8*>(&wlds[n * WSTRIDE + kc * 8]) =
          *reinterpret_cast<const u16x8*>(&Wt[n * D + kc * 8]);
    }
    __syncthreads();
    #pragma unroll
    for (int kb = 0; kb < 4; ++kb) {
      bf16x8 af0 = *reinterpret_cast<const bf16x8*>(&Act[a0 + kb * 32]);
      bf16x8 af1 = *reinterpret_cast<const bf16x8*>(&Act[a1 + kb * 32]);
      #pragma unroll
      for (int c = 0; c < 8; ++c) {
        bf16x8 wf = *reinterpret_cast<const bf16x8*>(
            &wlds[(c * 16 + l15) * WSTRIDE + kb * 32 + g * 8]);
        acc0[c] = __builtin_amdgcn_mfma_f32_16x16x32_bf16(af0, wf, acc0[c], 0, 0, 0);
        acc1[c] = __builtin_amdgcn_mfma_f32_16x16x32_bf16(af1, wf, acc1[c], 0, 0, 0);
      }
    }
    __syncthreads();
  }

  float wl[8], wr[8], bv[8];
  #pragma unroll
  for (int c = 0; c < 8; ++c) {
    wl[c] = Wl3[c * 16 + l15];
    wr[c] = Wr3[c * 16 + l15];
    bv[c] = bias[c * 16 + l15];
  }
  float bb3 = b3[0];
  #pragma unroll
  for (int rf = 0; rf < 2; ++rf) {
    #pragma unroll
    for (int rr = 0; rr < 4; ++rr) {
      float pz = 0.f, pr = 0.f;
      #pragma unroll
      for (int c = 0; c < 8; ++c) {
        float v = fmaxf((rf ? acc1[c][rr] : acc0[c][rr]) + bv[c], 0.f);
        pz += v * wl[c];
        pr += v * wr[c];
      }
      pz += __shfl_xor(pz, 1, 64); pr += __shfl_xor(pr, 1, 64);
      pz += __shfl_xor(pz, 2, 64); pr += __shfl_xor(pr, 2, 64);
      pz += __shfl_xor(pz, 4, 64); pr += __shfl_xor(pr, 4, 64);
      pz += __shfl_xor(pz, 8, 64); pr += __shfl_xor(pr, 8, 64);
      int row = rbase + rf * 16 + g * 4 + rr;
      if (l15 == 0 && row < NN) {
        z[row] = pz;
        r[row] = pr + bb3;
      }
    }
  }
}

// ---------------- final: out = r + mean(z over neighbors), 16 lanes/node ----
__global__ __launch_bounds__(256) void k_out(const float* __restrict__ z,
    const float* __restrict__ r, const int* __restrict__ rowstart,
    const int* __restrict__ col, float* __restrict__ out) {
  int t = threadIdx.x;
  int sub = t & 15;
  int node = blockIdx.x * 16 + (t >> 4);
  if (node >= NN) return;
  int b = rowstart[node], e = rowstart[node + 1];
  float s = 0.f;
  for (int j = b + sub; j < e; j += 16) s += z[col[j]];
  s += __shfl_xor(s, 1, 64);
  s += __shfl_xor(s, 2, 64);
  s += __shfl_xor(s, 4, 64);
  s += __shfl_xor(s, 8, 64);
  if (sub == 0) {
    float inv = (e > b) ? 1.f / (float)(e - b) : 0.f;
    out[node] = r[node] + s * inv;
  }
}

extern "C" void kernel_launch(void* const* d_in, const int* in_sizes, int n_in,
                              void* d_out, int out_size, void* d_ws, size_t ws_size,
                              hipStream_t stream) {
  const float* x   = (const float*)d_in[0];
  const int*   ei  = (const int*)d_in[1];
  const float* Wl1 = (const float*)d_in[2];
  const float* Wr1 = (const float*)d_in[3];
  const float* b1  = (const float*)d_in[4];
  const float* Wl2 = (const float*)d_in[5];
  const float* Wr2 = (const float*)d_in[6];
  const float* b2  = (const float*)d_in[7];
  const float* Wl3 = (const float*)d_in[8];
  const float* Wr3 = (const float*)d_in[9];
  const float* b3  = (const float*)d_in[10];
  const int* srcv = ei;
  const int* dstv = ei + NE;
  float* out = (float*)d_out;

  char* ws = (char*)d_ws;
  size_t off = 0;
  auto alloc = [&](size_t bytes) {
    size_t o = off;
    off += (bytes + 255) & ~(size_t)255;
    return o;
  };
  int* deg      = (int*)(ws + alloc((size_t)2 * NN * 4)); // deg + cursor contiguous
  int* cursor   = deg + NN;
  int* incl     = (int*)(ws + alloc((size_t)NN * 4));
  int* rowstart = (int*)(ws + alloc((size_t)(NN + 1) * 4));
  int* col      = (int*)(ws + alloc((size_t)NE * 4));
  int* bsum     = (int*)(ws + alloc(512 * 4));
  u16* xb   = (u16*)(ws + alloc((size_t)NN * D * 2));
  u16* Ab   = (u16*)(ws + alloc((size_t)NN * D * 2));
  u16* H1b  = (u16*)(ws + alloc((size_t)NN * D * 2));
  u16* Wt1l = (u16*)(ws + alloc((size_t)D * D * 2));
  u16* Wt1r = (u16*)(ws + alloc((size_t)D * D * 2));
  u16* Wt2l = (u16*)(ws + alloc((size_t)D * D * 2));
  u16* Wt2r = (u16*)(ws + alloc((size_t)D * D * 2));
  float* z  = (float*)(ws + alloc((size_t)NN * 4));
  float* r  = (float*)(ws + alloc((size_t)NN * 4));

  const int nb_nodes = (NN + 255) / 256;     // 391
  const int nb_edges = (NE + 255) / 256;     // 6250
  const int nb_gemm  = (NN + 127) / 128;     // 782
  const int nb_wave4 = (NN + 3) / 4;         // 25000
  const int nb_out   = (NN + 15) / 16;       // 6250
  const int nb_fill  = NGRP * ((NE + FILL_CHUNK - 1) / FILL_CHUNK);  // 8*782

  hipMemsetAsync(deg, 0, (size_t)2 * NN * 4, stream);

  // CSR build (+ x -> bf16 fused into count pass)
  k_count_cvt<<<nb_edges, 256, 0, stream>>>(dstv, deg, x, xb);
  k_scan1<<<nb_nodes, 256, 0, stream>>>(deg, incl, bsum);
  k_scan2<<<1, 512, 0, stream>>>(bsum, nb_nodes);
  k_scan3<<<nb_nodes, 256, 0, stream>>>(incl, deg, bsum, rowstart);
  k_fill<<<nb_fill, 256, 0, stream>>>(srcv, dstv, rowstart, cursor, col);

  // weight prep (transposed bf16)
  k_cvt_wt4<<<dim3(D, 4), D, 0, stream>>>(Wl1, Wr1, Wl2, Wr2, Wt1l, Wt1r, Wt2l, Wt2r);

  // layer 1
  k_agg_b<<<nb_wave4, 256, 0, stream>>>(xb, rowstart, col, Ab);
  k_gemm_mfma<<<nb_gemm, 256, 0, stream>>>(Ab, xb, Wt1l, Wt1r, b1, H1b);
  // layer 2 + fused layer-3 projection
  k_agg_b<<<nb_wave4, 256, 0, stream>>>(H1b, rowstart, col, Ab);
  k_gemm2_zr<<<nb_gemm, 256, 0, stream>>>(Ab, H1b, Wt2l, Wt2r, b2, Wl3, Wr3, b3, z, r);
  // final
  k_out<<<nb_out, 256, 0, stream>>>(z, r, rowstart, col, out);
}